// Round 7
// baseline (279.375 us; speedup 1.0000x reference)
//
#include <hip/hip_runtime.h>
#include <hip/hip_bf16.h>

#define BN   64
#define MAXN 512
#define DIM  512
#define NH   8
#define NS   32
#define NN   32768      // BN*MAXN
#define NE   524288
#define MP   (2048 * 512)   // one partial slice

typedef __hip_bfloat16 bf16;
using bf16x8 = __attribute__((ext_vector_type(8))) short;   // 8 bf16 (4 VGPRs)
using f32x4  = __attribute__((ext_vector_type(4))) float;

// ---- persistent device scratch ----
__device__ int   g_cnt[NN];
__device__ int   g_cur[NN];
__device__ int   g_off[NN + 1];
__device__ int   g_csr[NE];
__device__ float g_dinv[NN];
__device__ bf16  g_xb[NN * DIM];             // 32 MB
__device__ bf16  g_agg[NN * DIM];            // 32 MB
__device__ bf16  g_aggT[NN * DIM];           // 32 MB [b][d][n]
__device__ bf16  g_qf[256 * DIM];            // QF[h*32+s][d]
__device__ bf16  g_wob[DIM * DIM];           // Wo bf16
__device__ bf16  g_wvb[DIM * DIM];           // Wv bf16
__device__ bf16  g_wvo[DIM * 8 * DIM];       // 4 MB [e][h*512+d]
__device__ float g_bvo[DIM];
__device__ bf16  g_wffT[DIM * DIM];
__device__ float g_q[NS * DIM];
__device__ bf16  g_cp[BN * NS * 8 * DIM];    // ctxpre [b*32+s][h*512+d]
__device__ float g_part[4 * MP];             // split-K partials (16.8 MB, reused)
__device__ float g_h1[BN * NS * DIM];
__device__ bf16  g_h1b[BN * NS * DIM];

__device__ inline float bf2f(unsigned short u) {
    union { unsigned int i; float f; } x; x.i = ((unsigned int)u) << 16; return x.f;
}

__device__ inline void gll16(const bf16* g, bf16* l) {
    __builtin_amdgcn_global_load_lds(
        (const __attribute__((address_space(1))) void*)g,
        (__attribute__((address_space(3))) void*)l, 16, 0, 0);
}

// ---------------- graph preprocessing ----------------
__global__ void k_zero() {
    int i = blockIdx.x * 256 + threadIdx.x;
    if (i < NN) { g_cnt[i] = 0; g_cur[i] = 0; }
}

__global__ void k_count(const int* __restrict__ dst) {
    int e = blockIdx.x * 256 + threadIdx.x;
    if (e < NE) atomicAdd(&g_cnt[dst[e]], 1);
}

__global__ void k_scan() {
    __shared__ int part[1024];
    int t = threadIdx.x;
    int base = t * 32;
    int loc[32]; int s = 0;
#pragma unroll
    for (int i = 0; i < 32; i++) { loc[i] = g_cnt[base + i]; s += loc[i]; }
    part[t] = s; __syncthreads();
    for (int o = 1; o < 1024; o <<= 1) {
        int v = (t >= o) ? part[t - o] : 0;
        __syncthreads();
        part[t] += v;
        __syncthreads();
    }
    int ex = (t == 0) ? 0 : part[t - 1];
#pragma unroll
    for (int i = 0; i < 32; i++) {
        g_off[base + i] = ex; ex += loc[i];
        g_dinv[base + i] = rsqrtf(1.0f + (float)loc[i]);
    }
    if (t == 1023) g_off[NN] = ex;
}

__global__ void k_fill(const int* __restrict__ src, const int* __restrict__ dst) {
    int e = blockIdx.x * 256 + threadIdx.x;
    if (e < NE) {
        int d = dst[e];
        int p = atomicAdd(&g_cur[d], 1);
        g_csr[g_off[d] + p] = src[e];
    }
}

__global__ __launch_bounds__(256) void k_xb(const float* __restrict__ x) {
    long i = (long)(blockIdx.x * 256 + threadIdx.x) * 8;
    int node = (int)(i >> 9);
    float w = g_dinv[node];
    float4 a = *(const float4*)(x + i);
    float4 b = *(const float4*)(x + i + 4);
    float v[8] = {a.x, a.y, a.z, a.w, b.x, b.y, b.z, b.w};
    bf16x8 o;
#pragma unroll
    for (int j = 0; j < 8; j++) { bf16 t = __float2bfloat16(v[j] * w); o[j] = *(short*)&t; }
    *(bf16x8*)(g_xb + i) = o;
}

__global__ __launch_bounds__(256) void k_gather() {
    int bid = blockIdx.x;
    int lb = (bid & 7) * 1024 + (bid >> 3);
    int wave = threadIdx.x >> 6, lane = threadIdx.x & 63;
    int node = lb * 4 + wave;

    bf16x8 sv = ((const bf16x8*)(g_xb + (long)node * DIM))[lane];
    float acc[8];
#pragma unroll
    for (int j = 0; j < 8; j++) acc[j] = bf2f((unsigned short)sv[j]);

    int e = g_off[node], e1 = g_off[node + 1];
    for (; e + 4 <= e1; e += 4) {
        int s0 = g_csr[e], s1 = g_csr[e + 1], s2 = g_csr[e + 2], s3 = g_csr[e + 3];
        bf16x8 r0 = ((const bf16x8*)(g_xb + (long)s0 * DIM))[lane];
        bf16x8 r1 = ((const bf16x8*)(g_xb + (long)s1 * DIM))[lane];
        bf16x8 r2 = ((const bf16x8*)(g_xb + (long)s2 * DIM))[lane];
        bf16x8 r3 = ((const bf16x8*)(g_xb + (long)s3 * DIM))[lane];
#pragma unroll
        for (int j = 0; j < 8; j++)
            acc[j] += (bf2f((unsigned short)r0[j]) + bf2f((unsigned short)r1[j]))
                    + (bf2f((unsigned short)r2[j]) + bf2f((unsigned short)r3[j]));
    }
    for (; e < e1; e++) {
        int s0 = g_csr[e];
        bf16x8 r0 = ((const bf16x8*)(g_xb + (long)s0 * DIM))[lane];
#pragma unroll
        for (int j = 0; j < 8; j++) acc[j] += bf2f((unsigned short)r0[j]);
    }
    float dd = g_dinv[node];
    bf16x8 o;
#pragma unroll
    for (int j = 0; j < 8; j++) { bf16 t = __float2bfloat16(acc[j] * dd); o[j] = *(short*)&t; }
    ((bf16x8*)(g_agg + (long)node * DIM))[lane] = o;
}

// per-graph transpose: aggT[b][d][n] = agg[b*512+n][d]
__global__ __launch_bounds__(256) void k_aggT() {
    __shared__ unsigned short L[64][72];
    int id = blockIdx.x;
    int b = id >> 6, t = id & 63;
    int n0 = (t & 7) * 64, d0 = (t >> 3) * 64;
    int tid = threadIdx.x;
    const unsigned short* src = (const unsigned short*)g_agg + ((long)b * 512 + n0) * 512 + d0;
#pragma unroll
    for (int p = 0; p < 2; p++) {
        int r = (tid >> 3) + 32 * p, c = (tid & 7) * 8;
        *(int4*)&L[r][c] = *(const int4*)(src + (long)r * 512 + c);
    }
    __syncthreads();
    unsigned short* dst = (unsigned short*)g_aggT + ((long)b * 512 + d0) * 512 + n0;
#pragma unroll
    for (int p = 0; p < 2; p++) {
        int dr = (tid >> 3) + 32 * p, c0 = (tid & 7) * 8;
        unsigned short tmp[8];
#pragma unroll
        for (int j = 0; j < 8; j++) tmp[j] = L[c0 + j][dr];
        *(int4*)(dst + (long)dr * 512 + c0) = *(int4*)tmp;
    }
}

// ---------------- merged prep: qproj (64 blk) | cvt (384 blk) | bvo (2 blk) ----------------
__global__ __launch_bounds__(256) void k_prep(const float* __restrict__ seed,
                                              const float* __restrict__ Wq,
                                              const float* __restrict__ Wo,
                                              const float* __restrict__ Wv,
                                              const float* __restrict__ Wff,
                                              const float* __restrict__ bo,
                                              const float* __restrict__ bv) {
    int blk = blockIdx.x;
    if (blk < 64) {                       // q[s][e] = seed[s].Wq[e] / 8
        int i = blk * 256 + threadIdx.x;
        int s = i >> 9, e = i & 511;
        const float* sr = seed + s * DIM;
        const float* wr = Wq + e * DIM;
        float a0 = 0.f, a1 = 0.f;
        for (int d = 0; d < DIM; d += 8) {
            float4 a = *(const float4*)(sr + d);
            float4 b = *(const float4*)(wr + d);
            float4 c = *(const float4*)(sr + d + 4);
            float4 w = *(const float4*)(wr + d + 4);
            a0 += a.x * b.x + a.y * b.y + a.z * b.z + a.w * b.w;
            a1 += c.x * w.x + c.y * w.y + c.z * w.z + c.w * w.w;
        }
        g_q[i] = (a0 + a1) * 0.125f;
    } else if (blk < 448) {               // f32 -> bf16 weight convert
        long t = (long)(blk - 64) * 256 + threadIdx.x;
        const float* src; bf16* dst; long off;
        if (t < 32768)      { src = Wo;  dst = g_wob;  off = t; }
        else if (t < 65536) { src = Wv;  dst = g_wvb;  off = t - 32768; }
        else                { src = Wff; dst = g_wffT; off = t - 65536; }
        long i = off * 8;
        float4 a = *(const float4*)(src + i);
        float4 b = *(const float4*)(src + i + 4);
        float v[8] = {a.x, a.y, a.z, a.w, b.x, b.y, b.z, b.w};
        bf16x8 o;
#pragma unroll
        for (int j = 0; j < 8; j++) { bf16 q = __float2bfloat16(v[j]); o[j] = *(short*)&q; }
        *(bf16x8*)(dst + i) = o;
    } else {                              // bvo[e] = bo[e] + bv . Wo[e]
        int e = (blk - 448) * 256 + threadIdx.x;
        const float* orow = Wo + (long)e * DIM;
        float a0 = 0.f, a1 = 0.f;
        for (int c = 0; c < DIM; c += 8) {
            float4 a = *(const float4*)(bv + c);
            float4 w = *(const float4*)(orow + c);
            float4 x = *(const float4*)(bv + c + 4);
            float4 u = *(const float4*)(orow + c + 4);
            a0 += a.x * w.x + a.y * w.y + a.z * w.z + a.w * w.w;
            a1 += x.x * u.x + x.y * u.y + x.z * u.z + x.w * u.w;
        }
        g_bvo[e] = bo[e] + a0 + a1;
    }
}

// ---------------- shared 128x128 MFMA GEMM core (swizzled gll + dbuf) ----------------
__device__ __forceinline__ void gemm128(const bf16* __restrict__ A, long lda,
                                        const bf16* __restrict__ Bt, long ldb,
                                        long row0, long col0, int kbeg, int kend,
                                        bf16 (*As)[128 * 32], bf16 (*Bs)[128 * 32],
                                        f32x4 acc[4][4]) {
    int tid = threadIdx.x;
    int lane = tid & 63, wave = tid >> 6;
    int wr = wave >> 1, wc = wave & 1;
    int fr = lane & 15, fq = lane >> 4;
    int rchunk = (fq ^ ((fr >> 1) & 3)) * 8;
    int u0 = wave * 128 + lane;
    int sr0 = u0 >> 2, sc0 = ((u0 & 3) ^ ((sr0 >> 1) & 3)) * 8;
    int u1 = u0 + 64;
    int sr1 = u1 >> 2, sc1 = ((u1 & 3) ^ ((sr1 >> 1) & 3)) * 8;

    auto stage = [&](int buf, int kt) {
        gll16(A + (row0 + sr0) * lda + kt + sc0, As[buf] + u0 * 8);
        gll16(A + (row0 + sr1) * lda + kt + sc1, As[buf] + u1 * 8);
        gll16(Bt + (col0 + sr0) * ldb + kt + sc0, Bs[buf] + u0 * 8);
        gll16(Bt + (col0 + sr1) * ldb + kt + sc1, Bs[buf] + u1 * 8);
    };

    stage(0, kbeg);
    __syncthreads();
    for (int kt = kbeg; kt < kend; kt += 32) {
        int buf = ((kt - kbeg) >> 5) & 1;
        if (kt + 32 < kend) stage(buf ^ 1, kt + 32);
        bf16x8 af[4], bfv[4];
#pragma unroll
        for (int mi = 0; mi < 4; mi++)
            af[mi] = *(const bf16x8*)(As[buf] + (wr * 64 + mi * 16 + fr) * 32 + rchunk);
#pragma unroll
        for (int ni = 0; ni < 4; ni++)
            bfv[ni] = *(const bf16x8*)(Bs[buf] + (wc * 64 + ni * 16 + fr) * 32 + rchunk);
#pragma unroll
        for (int mi = 0; mi < 4; mi++)
#pragma unroll
            for (int ni = 0; ni < 4; ni++)
                acc[mi][ni] = __builtin_amdgcn_mfma_f32_16x16x32_bf16(af[mi], bfv[ni], acc[mi][ni], 0, 0, 0);
        __syncthreads();
    }
}

// merged: qf (512 blk, VALU) | wvo (128 blk, MFMA batched per head K=64)
__global__ __launch_bounds__(256) void k_qfwvo(const float* __restrict__ Wk) {
    __shared__ bf16 As[2][128 * 32];
    __shared__ bf16 Bs[2][128 * 32];
    int blk = blockIdx.x;
    if (blk < 512) {                      // QF[hs][d] = sum_dh q[s][h64+dh]*Wk[d][h64+dh]
        int i = blk * 256 + threadIdx.x;
        int hs = i >> 9, d = i & 511;
        int h = hs >> 5, s = hs & 31;
        const float* qr = g_q + s * DIM + h * 64;
        const float* wr = Wk + d * DIM + h * 64;
        float a0 = 0.f, a1 = 0.f;
        for (int t2 = 0; t2 < 64; t2 += 8) {
            float4 a = *(const float4*)(qr + t2);
            float4 w = *(const float4*)(wr + t2);
            float4 c = *(const float4*)(qr + t2 + 4);
            float4 u = *(const float4*)(wr + t2 + 4);
            a0 += a.x * w.x + a.y * w.y + a.z * w.z + a.w * w.w;
            a1 += c.x * u.x + c.y * u.y + c.z * u.z + c.w * u.w;
        }
        g_qf[i] = __float2bfloat16(a0 + a1);
    } else {                              // Wvo[e][h*512+d]
        int wi = blk - 512;
        int bx = wi & 3, by = (wi >> 2) & 3, h = wi >> 4;
        f32x4 acc[4][4];
#pragma unroll
        for (int i = 0; i < 4; i++)
#pragma unroll
            for (int j = 0; j < 4; j++) acc[i][j] = (f32x4){0.f, 0.f, 0.f, 0.f};
        int lane = threadIdx.x & 63;
        int wr = (threadIdx.x >> 6) >> 1, wc = (threadIdx.x >> 6) & 1;
        int fr = lane & 15, fq = lane >> 4;
        long row0 = (long)bx * 128, col0 = (long)by * 128;
        gemm128(g_wob, DIM, g_wvb, DIM, row0, col0, h * 64, h * 64 + 64, As, Bs, acc);
#pragma unroll
        for (int mi = 0; mi < 4; mi++)
#pragma unroll
            for (int ni = 0; ni < 4; ni++) {
                long col = col0 + wc * 64 + ni * 16 + fr;
#pragma unroll
                for (int r = 0; r < 4; r++) {
                    long row = row0 + wr * 64 + mi * 16 + fq * 4 + r;
                    g_wvo[row * 4096 + h * 512 + col] = __float2bfloat16(acc[mi][ni][r]);
                }
            }
    }
}

// ---------------- fused attention: scores + softmax + PV per (b,h) ----------------
// z head-major: b = z&63, h = z>>6  (one graph's 8 head-blocks share an XCD L2)
__global__ __launch_bounds__(256) void k_attn2() {
    __shared__ bf16 Bs[2][512 * 32];     // 64 KB staging (both phases)
    __shared__ bf16 Asq[2][32 * 32];     // 4 KB QF staging
    __shared__ bf16 P[32 * 512];         // 32 KB swizzled P
    __shared__ float redm[4][32];
    __shared__ float reds[4][32];
    int z = blockIdx.x;
    int b = z & 63, h = z >> 6;
    int tid = threadIdx.x, lane = tid & 63, w = tid >> 6;
    int fr = lane & 15, fq = lane >> 4;
    int rchunk = (fq ^ ((fr >> 1) & 3)) * 8;

    const bf16* Aq = g_qf + (long)(h * 32) * DIM;
    const bf16* Bn = g_agg + (long)b * ((long)MAXN * DIM);
    const bf16* Bd = g_aggT + (long)b * ((long)DIM * MAXN);

    int brow[8], bcol[8];
#pragma unroll
    for (int c = 0; c < 8; c++) {
        int u = tid + 256 * c;
        brow[c] = u >> 2;
        bcol[c] = ((u & 3) ^ ((brow[c] >> 1) & 3)) * 8;
    }
    int arow = tid >> 2;
    int acol = ((tid & 3) ^ ((arow >> 1) & 3)) * 8;

    f32x4 acc[2][8];
#pragma unroll
    for (int i = 0; i < 2; i++)
#pragma unroll
        for (int j = 0; j < 8; j++) acc[i][j] = (f32x4){0.f, 0.f, 0.f, 0.f};

    // ---- phase 1: S = QF_h . agg_b^T  (M=32, N=512, K=512) ----
    if (tid < 128) gll16(Aq + (long)arow * DIM + acol, Asq[0] + tid * 8);
#pragma unroll
    for (int c = 0; c < 8; c++)
        gll16(Bn + (long)brow[c] * DIM + bcol[c], Bs[0] + (tid + 256 * c) * 8);
    __syncthreads();
    for (int kt = 0; kt < 512; kt += 32) {
        int buf = (kt >> 5) & 1;
        if (kt + 32 < 512) {
            if (tid < 128) gll16(Aq + (long)arow * DIM + kt + 32 + acol, Asq[buf ^ 1] + tid * 8);
#pragma unroll
            for (int c = 0; c < 8; c++)
                gll16(Bn + (long)brow[c] * DIM + kt + 32 + bcol[c], Bs[buf ^ 1] + (tid + 256 * c) * 8);
        } else {
            // prefetch phase-2 tile 0 (Bs[0] free since step kt-32's barrier)
#pragma unroll
            for (int c = 0; c < 8; c++)
                gll16(Bd + (long)brow[c] * MAXN + bcol[c], Bs[0] + (tid + 256 * c) * 8);
        }
        bf16x8 af[2], bv8[8];
#pragma unroll
        for (int mi = 0; mi < 2; mi++)
            af[mi] = *(const bf16x8*)(Asq[buf] + (mi * 16 + fr) * 32 + rchunk);
#pragma unroll
        for (int nf = 0; nf < 8; nf++)
            bv8[nf] = *(const bf16x8*)(Bs[buf] + (w * 128 + nf * 16 + fr) * 32 + rchunk);
#pragma unroll
        for (int mi = 0; mi < 2; mi++)
#pragma unroll
            for (int nf = 0; nf < 8; nf++)
                acc[mi][nf] = __builtin_amdgcn_mfma_f32_16x16x32_bf16(af[mi], bv8[nf], acc[mi][nf], 0, 0, 0);
        __syncthreads();
    }

    // ---- softmax: rows mi*16+fq*4+r (hs), cols w*128+nf*16+fr (n) ----
#pragma unroll
    for (int mi = 0; mi < 2; mi++)
#pragma unroll
        for (int r = 0; r < 4; r++) {
            float m = acc[mi][0][r];
#pragma unroll
            for (int nf = 1; nf < 8; nf++) m = fmaxf(m, acc[mi][nf][r]);
#pragma unroll
            for (int o = 1; o < 16; o <<= 1) m = fmaxf(m, __shfl_xor(m, o));
            if (fr == 0) redm[w][mi * 16 + fq * 4 + r] = m;
        }
    __syncthreads();
#pragma unroll
    for (int mi = 0; mi < 2; mi++)
#pragma unroll
        for (int r = 0; r < 4; r++) {
            int row = mi * 16 + fq * 4 + r;
            float M = fmaxf(fmaxf(redm[0][row], redm[1][row]), fmaxf(redm[2][row], redm[3][row]));
            float s = 0.f;
#pragma unroll
            for (int nf = 0; nf < 8; nf++) {
                float e = __expf(acc[mi][nf][r] - M);
                acc[mi][nf][r] = e; s += e;
            }
#pragma unroll
            for (int o = 1; o < 16; o <<= 1) s += __shfl_xor(s, o);
            if (fr == 0) reds[w][row] = s;
        }
    __syncthreads();
#pragma unroll
    for (int mi = 0; mi < 2; mi++)
#pragma unroll
        for (int r = 0; r < 4; r++) {
            int row = mi * 16 + fq * 4 + r;
            float iv = 1.0f / (reds[0][row] + reds[1][row] + reds[2][row] + reds[3][row]);
#pragma unroll
            for (int nf = 0; nf < 8; nf++) {
                int col = w * 128 + nf * 16 + fr;
                int ch = (col >> 3) ^ (row & 7);
                P[row * 512 + ch * 8 + (col & 7)] = __float2bfloat16(acc[mi][nf][r] * iv);
            }
        }
    __syncthreads();

    // ---- phase 2: ctxpre = P . agg_b  via aggT  (M=32, N=512 d, K=512 n) ----
#pragma unroll
    for (int i = 0; i < 2; i++)
#pragma unroll
        for (int j = 0; j < 8; j++) acc[i][j] = (f32x4){0.f, 0.f, 0.f, 0.f};
    for (int kt = 0; kt < 512; kt += 32) {
        int buf = (kt >> 5) & 1;
        if (kt + 32 < 512) {
#pragma unroll
            for (int c = 0; c < 8; c++)
                gll16(Bd + (long)brow[c] * MAXN + kt + 32 + bcol[c], Bs[buf ^ 1] + (tid + 256 * c) * 8);
        }
        bf16x8 af2[2], bv8[8];
#pragma unroll
        for (int mi = 0; mi < 2; mi++) {
            int row = mi * 16 + fr;
            int ch = ((kt >> 3) + fq) ^ (row & 7);
            af2[mi] = *(const bf16x8*)(P + row * 512 + ch * 8);
        }
#pragma unroll
        for (int nf = 0; nf < 8; nf++)
            bv8[nf] = *(const bf16x8*)(Bs[buf] + (w * 128 + nf * 16 + fr) * 32 + rchunk);
#pragma unroll
        for (int mi = 0; mi < 2; mi++)
#pragma unroll
            for (int nf = 0; nf < 8; nf++)
                acc[mi][nf] = __builtin_amdgcn_mfma_f32_16x16x32_bf16(af2[mi], bv8[nf], acc[mi][nf], 0, 0, 0);
        __syncthreads();
    }
#pragma unroll
    for (int mi = 0; mi < 2; mi++)
#pragma unroll
        for (int nf = 0; nf < 8; nf++) {
            int d = w * 128 + nf * 16 + fr;
#pragma unroll
            for (int r = 0; r < 4; r++) {
                int s = mi * 16 + fq * 4 + r;
                g_cp[((long)b * NS + s) * 4096 + h * 512 + d] = __float2bfloat16(acc[mi][nf][r]);
            }
        }
}

#define GEMM_PROLOGUE                                        \
    __shared__ bf16 As[2][128 * 32];                         \
    __shared__ bf16 Bs[2][128 * 32];                         \
    f32x4 acc[4][4];                                         \
    _Pragma("unroll")                                        \
    for (int i = 0; i < 4; i++)                              \
        _Pragma("unroll")                                    \
        for (int j = 0; j < 4; j++) acc[i][j] = (f32x4){0.f, 0.f, 0.f, 0.f}; \
    int lane = threadIdx.x & 63, wave = threadIdx.x >> 6;    \
    int wr = wave >> 1, wc = wave & 1;                       \
    int fr = lane & 15, fq = lane >> 4;

// attn_out partials: A=g_cp [2048][4096], Bt=g_wvo [512][4096], 4-way split-K
__global__ __launch_bounds__(256) void k_vo() {
    GEMM_PROLOGUE
    int z = blockIdx.z;
    long row0 = (long)blockIdx.x * 128, col0 = (long)blockIdx.y * 128;
    gemm128(g_cp, 4096, g_wvo, 4096, row0, col0, z * 1024, z * 1024 + 1024, As, Bs, acc);
    float* out = g_part + (long)z * MP;
#pragma unroll
    for (int mi = 0; mi < 4; mi++)
#pragma unroll
        for (int ni = 0; ni < 4; ni++) {
            long col = col0 + wc * 64 + ni * 16 + fr;
#pragma unroll
            for (int r = 0; r < 4; r++) {
                long row = row0 + wr * 64 + mi * 16 + fq * 4 + r;
                out[row * DIM + col] = acc[mi][ni][r];
            }
        }
}

// FFN partials: A=g_h1b [2048][512], Bt=g_wffT [512][512], 4-way split-K
__global__ __launch_bounds__(256) void k_ffn() {
    GEMM_PROLOGUE
    int z = blockIdx.z;
    long row0 = (long)blockIdx.x * 128, col0 = (long)blockIdx.y * 128;
    gemm128(g_h1b, DIM, g_wffT, DIM, row0, col0, z * 128, z * 128 + 128, As, Bs, acc);
    float* out = g_part + (long)z * MP;
#pragma unroll
    for (int mi = 0; mi < 4; mi++)
#pragma unroll
        for (int ni = 0; ni < 4; ni++) {
            long col = col0 + wc * 64 + ni * 16 + fr;
#pragma unroll
            for (int r = 0; r < 4; r++) {
                long row = row0 + wr * 64 + mi * 16 + fq * 4 + r;
                out[row * DIM + col] = acc[mi][ni][r];
            }
        }
}

// ---------------- layernorms (fused split-K reduction + bias) ----------------
__device__ inline float blockReduceSum(float v, float* red, int tid) {
#pragma unroll
    for (int o = 32; o > 0; o >>= 1) v += __shfl_xor(v, o);
    __syncthreads();
    if ((tid & 63) == 0) red[tid >> 6] = v;
    __syncthreads();
    return red[0] + red[1] + red[2] + red[3];
}

__global__ __launch_bounds__(256) void k_ln1(const float* __restrict__ seed,
                                             const float* __restrict__ gamma,
                                             const float* __restrict__ beta) {
    __shared__ float red[4];
    int r = blockIdx.x, t = threadIdx.x;
    int s = r & 31;
    long base = (long)r * DIM;
    float v0 = seed[s * DIM + t] + g_bvo[t];
    float v1 = seed[s * DIM + 256 + t] + g_bvo[256 + t];
#pragma unroll
    for (int z = 0; z < 4; z++) {
        v0 += g_part[(long)z * MP + base + t];
        v1 += g_part[(long)z * MP + base + 256 + t];
    }
    float mean = blockReduceSum(v0 + v1, red, t) * (1.0f / DIM);
    float d0 = v0 - mean, d1 = v1 - mean;
    float var = blockReduceSum(d0 * d0 + d1 * d1, red, t) * (1.0f / DIM);
    float ri = rsqrtf(var + 1e-5f);
    float o0 = d0 * ri * gamma[t] + beta[t];
    float o1 = d1 * ri * gamma[256 + t] + beta[256 + t];
    g_h1[base + t] = o0; g_h1[base + 256 + t] = o1;
    g_h1b[base + t] = __float2bfloat16(o0);
    g_h1b[base + 256 + t] = __float2bfloat16(o1);
}

__global__ __launch_bounds__(256) void k_ln2(const float* __restrict__ gamma,
                                             const float* __restrict__ beta,
                                             const float* __restrict__ bff,
                                             float* __restrict__ out) {
    __shared__ float red[4];
    int r = blockIdx.x, t = threadIdx.x;
    long base = (long)r * DIM;
    float v0 = g_h1[base + t] + bff[t];
    float v1 = g_h1[base + 256 + t] + bff[256 + t];
#pragma unroll
    for (int z = 0; z < 4; z++) {
        v0 += g_part[(long)z * MP + base + t];
        v1 += g_part[(long)z * MP + base + 256 + t];
    }
    float mean = blockReduceSum(v0 + v1, red, t) * (1.0f / DIM);
    float d0 = v0 - mean, d1 = v1 - mean;
    float var = blockReduceSum(d0 * d0 + d1 * d1, red, t) * (1.0f / DIM);
    float ri = rsqrtf(var + 1e-5f);
    out[base + t] = d0 * ri * gamma[t] + beta[t];
    out[base + 256 + t] = d1 * ri * gamma[256 + t] + beta[256 + t];
}

// ---------------- launch ----------------
extern "C" void kernel_launch(void* const* d_in, const int* in_sizes, int n_in,
                              void* d_out, int out_size, void* d_ws, size_t ws_size,
                              hipStream_t stream) {
    (void)in_sizes; (void)n_in; (void)out_size; (void)d_ws; (void)ws_size;
    const float* x    = (const float*)d_in[1];
    const int*   ei   = (const int*)d_in[2];
    const int*   esrc = ei;
    const int*   edst = ei + NE;
    const float* seed = (const float*)d_in[4];
    const float* Wk   = (const float*)d_in[5];
    const float* Wv   = (const float*)d_in[7];
    const float* bv   = (const float*)d_in[8];
    const float* Wq   = (const float*)d_in[9];
    const float* Wo   = (const float*)d_in[10];
    const float* bo   = (const float*)d_in[11];
    const float* Wff  = (const float*)d_in[12];
    const float* bff  = (const float*)d_in[13];
    const float* gh   = (const float*)d_in[14];
    const float* bh   = (const float*)d_in[15];
    const float* gz   = (const float*)d_in[16];
    const float* bz   = (const float*)d_in[17];
    float* out = (float*)d_out;

    k_zero <<<NN / 256, 256, 0, stream>>>();
    k_count<<<NE / 256, 256, 0, stream>>>(edst);
    k_scan <<<1, 1024, 0, stream>>>();
    k_fill <<<NE / 256, 256, 0, stream>>>(esrc, edst);
    k_xb   <<<(NN * DIM) / (256 * 8), 256, 0, stream>>>(x);
    k_gather<<<NN / 4, 256, 0, stream>>>();
    k_aggT <<<BN * 64, 256, 0, stream>>>();
    k_prep <<<450, 256, 0, stream>>>(seed, Wq, Wo, Wv, Wff, bo, bv);
    k_qfwvo<<<640, 256, 0, stream>>>(Wk);

    k_attn2<<<512, 256, 0, stream>>>();

    k_vo <<<dim3(16, 4, 4), 256, 0, stream>>>();
    k_ln1<<<BN * NS, 256, 0, stream>>>(seed, gh, bh);
    k_ffn<<<dim3(16, 4, 4), 256, 0, stream>>>();
    k_ln2<<<BN * NS, 256, 0, stream>>>(gz, bz, bff, out);
}

// Round 8
// 253.578 us; speedup vs baseline: 1.1017x; 1.1017x over previous
//
#include <hip/hip_runtime.h>
#include <hip/hip_bf16.h>

#define BN   64
#define MAXN 512
#define DIM  512
#define NH   8
#define NS   32
#define NN   32768      // BN*MAXN
#define NE   524288
#define MP   (2048 * 512)   // one partial slice

typedef __hip_bfloat16 bf16;
using bf16x8 = __attribute__((ext_vector_type(8))) short;   // 8 bf16 (4 VGPRs)
using f32x4  = __attribute__((ext_vector_type(4))) float;

// ---- persistent device scratch ----
__device__ int   g_cnt[NN];
__device__ int   g_cur[NN];
__device__ int   g_off[NN + 1];
__device__ int   g_csr[NE];
__device__ float g_dinv[NN];
__device__ bf16  g_xb[NN * DIM];             // 32 MB
__device__ bf16  g_agg[NN * DIM];            // 32 MB
__device__ bf16  g_aggT[NN * DIM];           // 32 MB [b][d][n]
__device__ bf16  g_qf[256 * DIM];            // QF[h*32+s][d]
__device__ bf16  g_wob[DIM * DIM];           // Wo bf16
__device__ bf16  g_wvb[DIM * DIM];           // Wv bf16
__device__ bf16  g_wvo[DIM * 8 * DIM];       // 4 MB [e][h*512+d]
__device__ float g_bvo[DIM];
__device__ bf16  g_wffT[DIM * DIM];
__device__ float g_q[NS * DIM];
__device__ bf16  g_sc[BN * 256 * MAXN];      // scores -> P (in-place softmax)
__device__ bf16  g_cp[BN * NS * 8 * DIM];    // ctxpre [b*32+s][h*512+d]
__device__ float g_part[4 * MP];             // split-K partials
__device__ float g_h1[BN * NS * DIM];
__device__ bf16  g_h1b[BN * NS * DIM];

__device__ inline float bf2f(unsigned short u) {
    union { unsigned int i; float f; } x; x.i = ((unsigned int)u) << 16; return x.f;
}

__device__ inline void gll16(const bf16* g, bf16* l) {
    __builtin_amdgcn_global_load_lds(
        (const __attribute__((address_space(1))) void*)g,
        (__attribute__((address_space(3))) void*)l, 16, 0, 0);
}

// ---------------- graph preprocessing ----------------
__global__ void k_zero() {
    int i = blockIdx.x * 256 + threadIdx.x;
    if (i < NN) { g_cnt[i] = 0; g_cur[i] = 0; }
}

// merged: edge-count (2048 blk) | qproj (64) | weight cvt (384) | bvo (2)
__global__ __launch_bounds__(256) void k_cntprep(const int* __restrict__ dst,
                                                 const float* __restrict__ seed,
                                                 const float* __restrict__ Wq,
                                                 const float* __restrict__ Wo,
                                                 const float* __restrict__ Wv,
                                                 const float* __restrict__ Wff,
                                                 const float* __restrict__ bo,
                                                 const float* __restrict__ bv) {
    int blk = blockIdx.x;
    if (blk < 2048) {
        int e = blk * 256 + threadIdx.x;
        atomicAdd(&g_cnt[dst[e]], 1);
    } else if (blk < 2112) {              // q[s][e] = seed[s].Wq[e] / 8
        int i = (blk - 2048) * 256 + threadIdx.x;
        int s = i >> 9, e = i & 511;
        const float* sr = seed + s * DIM;
        const float* wr = Wq + e * DIM;
        float a0 = 0.f, a1 = 0.f;
        for (int d = 0; d < DIM; d += 8) {
            float4 a = *(const float4*)(sr + d);
            float4 b = *(const float4*)(wr + d);
            float4 c = *(const float4*)(sr + d + 4);
            float4 w = *(const float4*)(wr + d + 4);
            a0 += a.x * b.x + a.y * b.y + a.z * b.z + a.w * b.w;
            a1 += c.x * w.x + c.y * w.y + c.z * w.z + c.w * w.w;
        }
        g_q[i] = (a0 + a1) * 0.125f;
    } else if (blk < 2496) {              // f32 -> bf16 weight convert
        long t = (long)(blk - 2112) * 256 + threadIdx.x;
        const float* src; bf16* dstp; long off;
        if (t < 32768)      { src = Wo;  dstp = g_wob;  off = t; }
        else if (t < 65536) { src = Wv;  dstp = g_wvb;  off = t - 32768; }
        else                { src = Wff; dstp = g_wffT; off = t - 65536; }
        long i = off * 8;
        float4 a = *(const float4*)(src + i);
        float4 b = *(const float4*)(src + i + 4);
        float v[8] = {a.x, a.y, a.z, a.w, b.x, b.y, b.z, b.w};
        bf16x8 o;
#pragma unroll
        for (int j = 0; j < 8; j++) { bf16 q = __float2bfloat16(v[j]); o[j] = *(short*)&q; }
        *(bf16x8*)(dstp + i) = o;
    } else {                              // bvo[e] = bo[e] + bv . Wo[e]
        int e = (blk - 2496) * 256 + threadIdx.x;
        const float* orow = Wo + (long)e * DIM;
        float a0 = 0.f, a1 = 0.f;
        for (int c = 0; c < DIM; c += 8) {
            float4 a = *(const float4*)(bv + c);
            float4 w = *(const float4*)(orow + c);
            float4 xx = *(const float4*)(bv + c + 4);
            float4 u = *(const float4*)(orow + c + 4);
            a0 += a.x * w.x + a.y * w.y + a.z * w.z + a.w * w.w;
            a1 += xx.x * u.x + xx.y * u.y + xx.z * u.z + xx.w * u.w;
        }
        g_bvo[e] = bo[e] + a0 + a1;
    }
}

__global__ void k_scan() {
    __shared__ int part[1024];
    int t = threadIdx.x;
    int base = t * 32;
    int loc[32]; int s = 0;
#pragma unroll
    for (int i = 0; i < 32; i++) { loc[i] = g_cnt[base + i]; s += loc[i]; }
    part[t] = s; __syncthreads();
    for (int o = 1; o < 1024; o <<= 1) {
        int v = (t >= o) ? part[t - o] : 0;
        __syncthreads();
        part[t] += v;
        __syncthreads();
    }
    int ex = (t == 0) ? 0 : part[t - 1];
#pragma unroll
    for (int i = 0; i < 32; i++) {
        g_off[base + i] = ex; ex += loc[i];
        g_dinv[base + i] = rsqrtf(1.0f + (float)loc[i]);
    }
    if (t == 1023) g_off[NN] = ex;
}

// ---------------- shared 128x128 MFMA GEMM core (swizzled gll + dbuf) ----------------
__device__ __forceinline__ void gemm128(const bf16* __restrict__ A, long lda,
                                        const bf16* __restrict__ Bt, long ldb,
                                        long row0, long col0, int kbeg, int kend,
                                        bf16 (*As)[128 * 32], bf16 (*Bs)[128 * 32],
                                        f32x4 acc[4][4]) {
    int tid = threadIdx.x;
    int lane = tid & 63, wave = tid >> 6;
    int wr = wave >> 1, wc = wave & 1;
    int fr = lane & 15, fq = lane >> 4;
    int rchunk = (fq ^ ((fr >> 1) & 3)) * 8;
    int u0 = wave * 128 + lane;
    int sr0 = u0 >> 2, sc0 = ((u0 & 3) ^ ((sr0 >> 1) & 3)) * 8;
    int u1 = u0 + 64;
    int sr1 = u1 >> 2, sc1 = ((u1 & 3) ^ ((sr1 >> 1) & 3)) * 8;

    auto stage = [&](int buf, int kt) {
        gll16(A + (row0 + sr0) * lda + kt + sc0, As[buf] + u0 * 8);
        gll16(A + (row0 + sr1) * lda + kt + sc1, As[buf] + u1 * 8);
        gll16(Bt + (col0 + sr0) * ldb + kt + sc0, Bs[buf] + u0 * 8);
        gll16(Bt + (col0 + sr1) * ldb + kt + sc1, Bs[buf] + u1 * 8);
    };

    stage(0, kbeg);
    __syncthreads();
    for (int kt = kbeg; kt < kend; kt += 32) {
        int buf = ((kt - kbeg) >> 5) & 1;
        if (kt + 32 < kend) stage(buf ^ 1, kt + 32);
        bf16x8 af[4], bfv[4];
#pragma unroll
        for (int mi = 0; mi < 4; mi++)
            af[mi] = *(const bf16x8*)(As[buf] + (wr * 64 + mi * 16 + fr) * 32 + rchunk);
#pragma unroll
        for (int ni = 0; ni < 4; ni++)
            bfv[ni] = *(const bf16x8*)(Bs[buf] + (wc * 64 + ni * 16 + fr) * 32 + rchunk);
#pragma unroll
        for (int mi = 0; mi < 4; mi++)
#pragma unroll
            for (int ni = 0; ni < 4; ni++)
                acc[mi][ni] = __builtin_amdgcn_mfma_f32_16x16x32_bf16(af[mi], bfv[ni], acc[mi][ni], 0, 0, 0);
        __syncthreads();
    }
}

#define ACC_INIT                                             \
    f32x4 acc[4][4];                                         \
    _Pragma("unroll")                                        \
    for (int i = 0; i < 4; i++)                              \
        _Pragma("unroll")                                    \
        for (int j = 0; j < 4; j++) acc[i][j] = (f32x4){0.f, 0.f, 0.f, 0.f}; \
    int lane = threadIdx.x & 63, wave = threadIdx.x >> 6;    \
    int wr = wave >> 1, wc = wave & 1;                       \
    int fr = lane & 15, fq = lane >> 4;

// merged: fill (2048 blk) | xb (8192 blk) | qf (512) | wvo (128)
__global__ __launch_bounds__(256) void k_fillxb(const int* __restrict__ src,
                                                const int* __restrict__ dst,
                                                const float* __restrict__ x,
                                                const float* __restrict__ Wk) {
    __shared__ bf16 As[2][128 * 32];
    __shared__ bf16 Bs[2][128 * 32];
    int blk = blockIdx.x;
    if (blk < 2048) {                     // CSR fill
        int e = blk * 256 + threadIdx.x;
        int d = dst[e];
        int p = atomicAdd(&g_cur[d], 1);
        g_csr[g_off[d] + p] = src[e];
    } else if (blk < 10240) {             // xb = bf16(x * dinv)
        long i = (long)(blk - 2048) * (256 * 8) + (long)threadIdx.x * 8;
        int node = (int)(i >> 9);
        float w = g_dinv[node];
        float4 a = *(const float4*)(x + i);
        float4 b = *(const float4*)(x + i + 4);
        float v[8] = {a.x, a.y, a.z, a.w, b.x, b.y, b.z, b.w};
        bf16x8 o;
#pragma unroll
        for (int j = 0; j < 8; j++) { bf16 t = __float2bfloat16(v[j] * w); o[j] = *(short*)&t; }
        *(bf16x8*)(g_xb + i) = o;
    } else if (blk < 10752) {             // QF[hs][d]
        int i = (blk - 10240) * 256 + threadIdx.x;
        int hs = i >> 9, d = i & 511;
        int h = hs >> 5, s = hs & 31;
        const float* qr = g_q + s * DIM + h * 64;
        const float* wr = Wk + d * DIM + h * 64;
        float a0 = 0.f, a1 = 0.f;
        for (int t2 = 0; t2 < 64; t2 += 8) {
            float4 a = *(const float4*)(qr + t2);
            float4 w = *(const float4*)(wr + t2);
            float4 c = *(const float4*)(qr + t2 + 4);
            float4 u = *(const float4*)(wr + t2 + 4);
            a0 += a.x * w.x + a.y * w.y + a.z * w.z + a.w * w.w;
            a1 += c.x * u.x + c.y * u.y + c.z * u.z + c.w * u.w;
        }
        g_qf[i] = __float2bfloat16(a0 + a1);
    } else {                              // Wvo GEMM, batched per head (K=64)
        int wi = blk - 10752;
        int bx = wi & 3, by = (wi >> 2) & 3, h = wi >> 4;
        ACC_INIT
        long row0 = (long)bx * 128, col0 = (long)by * 128;
        gemm128(g_wob, DIM, g_wvb, DIM, row0, col0, h * 64, h * 64 + 64, As, Bs, acc);
#pragma unroll
        for (int mi = 0; mi < 4; mi++)
#pragma unroll
            for (int ni = 0; ni < 4; ni++) {
                long col = col0 + wc * 64 + ni * 16 + fr;
#pragma unroll
                for (int r = 0; r < 4; r++) {
                    long row = row0 + wr * 64 + mi * 16 + fq * 4 + r;
                    g_wvo[row * 4096 + h * 512 + col] = __float2bfloat16(acc[mi][ni][r]);
                }
            }
    }
}

// gather (unroll 8): agg[d] = bf16( dinv[d] * ( xb[d] + sum xb[src] ) )
__global__ __launch_bounds__(256) void k_gather() {
    int bid = blockIdx.x;
    int lb = (bid & 7) * 1024 + (bid >> 3);
    int wave = threadIdx.x >> 6, lane = threadIdx.x & 63;
    int node = lb * 4 + wave;

    bf16x8 sv = ((const bf16x8*)(g_xb + (long)node * DIM))[lane];
    float acc[8];
#pragma unroll
    for (int j = 0; j < 8; j++) acc[j] = bf2f((unsigned short)sv[j]);

    int e = g_off[node], e1 = g_off[node + 1];
    for (; e + 8 <= e1; e += 8) {
        bf16x8 r[8];
#pragma unroll
        for (int q = 0; q < 8; q++)
            r[q] = ((const bf16x8*)(g_xb + (long)g_csr[e + q] * DIM))[lane];
#pragma unroll
        for (int j = 0; j < 8; j++) {
            float s01 = bf2f((unsigned short)r[0][j]) + bf2f((unsigned short)r[1][j]);
            float s23 = bf2f((unsigned short)r[2][j]) + bf2f((unsigned short)r[3][j]);
            float s45 = bf2f((unsigned short)r[4][j]) + bf2f((unsigned short)r[5][j]);
            float s67 = bf2f((unsigned short)r[6][j]) + bf2f((unsigned short)r[7][j]);
            acc[j] += (s01 + s23) + (s45 + s67);
        }
    }
    for (; e < e1; e++) {
        bf16x8 r0 = ((const bf16x8*)(g_xb + (long)g_csr[e] * DIM))[lane];
#pragma unroll
        for (int j = 0; j < 8; j++) acc[j] += bf2f((unsigned short)r0[j]);
    }
    float dd = g_dinv[node];
    bf16x8 o;
#pragma unroll
    for (int j = 0; j < 8; j++) { bf16 t = __float2bfloat16(acc[j] * dd); o[j] = *(short*)&t; }
    ((bf16x8*)(g_agg + (long)node * DIM))[lane] = o;
}

// merged: scores (512 blk, graph-major XCD swizzle) | aggT (4096 blk)
__global__ __launch_bounds__(256) void k_aggsc() {
    __shared__ __align__(16) char smem[32768];
    int blk = blockIdx.x;
    if (blk < 512) {                      // scores: C[hs][n] = QF . agg_b^T
        bf16 (*As)[128 * 32] = (bf16(*)[128 * 32])smem;
        bf16 (*Bs)[128 * 32] = (bf16(*)[128 * 32])(smem + 16384);
        int b = blk & 63, bx = (blk >> 6) & 1, by = blk >> 7;
        ACC_INIT
        long row0 = (long)bx * 128, col0 = (long)by * 128;
        gemm128(g_qf, DIM, g_agg + (long)b * (MAXN * DIM), DIM, row0, col0, 0, DIM, As, Bs, acc);
        bf16* out = g_sc + (long)b * (256 * MAXN);
#pragma unroll
        for (int mi = 0; mi < 4; mi++)
#pragma unroll
            for (int ni = 0; ni < 4; ni++) {
                long col = col0 + wc * 64 + ni * 16 + fr;
#pragma unroll
                for (int r = 0; r < 4; r++) {
                    long row = row0 + wr * 64 + mi * 16 + fq * 4 + r;
                    out[row * MAXN + col] = __float2bfloat16(acc[mi][ni][r]);
                }
            }
    } else {                              // aggT[b][d][n] = agg[b*512+n][d]
        unsigned short (*L)[72] = (unsigned short(*)[72])smem;
        int id = blk - 512;
        int b = id >> 6, t = id & 63;
        int n0 = (t & 7) * 64, d0 = (t >> 3) * 64;
        int tid = threadIdx.x;
        const unsigned short* src = (const unsigned short*)g_agg + ((long)b * 512 + n0) * 512 + d0;
#pragma unroll
        for (int p = 0; p < 2; p++) {
            int r = (tid >> 3) + 32 * p, c = (tid & 7) * 8;
            *(int4*)&L[r][c] = *(const int4*)(src + (long)r * 512 + c);
        }
        __syncthreads();
        unsigned short* dst = (unsigned short*)g_aggT + ((long)b * 512 + d0) * 512 + n0;
#pragma unroll
        for (int p = 0; p < 2; p++) {
            int dr = (tid >> 3) + 32 * p, c0 = (tid & 7) * 8;
            unsigned short tmp[8];
#pragma unroll
            for (int j = 0; j < 8; j++) tmp[j] = L[c0 + j][dr];
            *(int4*)(dst + (long)dr * 512 + c0) = *(int4*)tmp;
        }
    }
}

// in-place row softmax on g_sc (16384 rows of 512)
__global__ __launch_bounds__(256) void k_soft() {
    int w = threadIdx.x >> 6, lane = threadIdx.x & 63;
    unsigned short* base = (unsigned short*)g_sc + ((long)blockIdx.x * 16 + w * 4) * MAXN;
#pragma unroll
    for (int r = 0; r < 4; r++) {
        unsigned short* row = base + (long)r * MAXN;
        float v[8]; float m = -1e30f;
#pragma unroll
        for (int k = 0; k < 8; k++) { v[k] = bf2f(row[lane + 64 * k]); m = fmaxf(m, v[k]); }
#pragma unroll
        for (int o = 32; o > 0; o >>= 1) m = fmaxf(m, __shfl_xor(m, o));
        float sum = 0.f;
#pragma unroll
        for (int k = 0; k < 8; k++) { v[k] = __expf(v[k] - m); sum += v[k]; }
#pragma unroll
        for (int o = 32; o > 0; o >>= 1) sum += __shfl_xor(sum, o);
        float inv = 1.0f / sum;
#pragma unroll
        for (int k = 0; k < 8; k++) {
            bf16 t = __float2bfloat16(v[k] * inv);
            row[lane + 64 * k] = *(unsigned short*)&t;
        }
    }
}

// ctxpre: per (b,dh): C[hs][d] = P_b[hs][:] . aggT_b[dh*256+d][:]  (graph-major swizzle)
__global__ __launch_bounds__(256) void k_pvg() {
    __shared__ bf16 As[2][128 * 32];
    __shared__ bf16 Bs[2][128 * 32];
    int blk = blockIdx.x;
    int b = blk & 63, bx = (blk >> 6) & 1, by = (blk >> 7) & 1, dh = blk >> 8;
    ACC_INIT
    long row0 = (long)bx * 128, col0 = (long)by * 128;
    gemm128(g_sc + (long)b * (256 * MAXN), MAXN,
            g_aggT + (long)b * (DIM * MAXN) + (long)dh * (256 * MAXN), MAXN,
            row0, col0, 0, MAXN, As, Bs, acc);
#pragma unroll
    for (int mi = 0; mi < 4; mi++)
#pragma unroll
        for (int ni = 0; ni < 4; ni++) {
            long col = col0 + wc * 64 + ni * 16 + fr;
#pragma unroll
            for (int r = 0; r < 4; r++) {
                long row = row0 + wr * 64 + mi * 16 + fq * 4 + r;   // hs
                g_cp[((long)b * NS + (row & 31)) * 4096 + (row >> 5) * 512 + dh * 256 + col] =
                    __float2bfloat16(acc[mi][ni][r]);
            }
        }
}

// attn_out partials: A=g_cp [2048][4096], Bt=g_wvo [512][4096], 4-way split-K
__global__ __launch_bounds__(256) void k_vo() {
    __shared__ bf16 As[2][128 * 32];
    __shared__ bf16 Bs[2][128 * 32];
    ACC_INIT
    int z = blockIdx.z;
    long row0 = (long)blockIdx.x * 128, col0 = (long)blockIdx.y * 128;
    gemm128(g_cp, 4096, g_wvo, 4096, row0, col0, z * 1024, z * 1024 + 1024, As, Bs, acc);
    float* out = g_part + (long)z * MP;
#pragma unroll
    for (int mi = 0; mi < 4; mi++)
#pragma unroll
        for (int ni = 0; ni < 4; ni++) {
            long col = col0 + wc * 64 + ni * 16 + fr;
#pragma unroll
            for (int r = 0; r < 4; r++) {
                long row = row0 + wr * 64 + mi * 16 + fq * 4 + r;
                out[row * DIM + col] = acc[mi][ni][r];
            }
        }
}

// FFN partials: A=g_h1b [2048][512], Bt=g_wffT [512][512], 4-way split-K
__global__ __launch_bounds__(256) void k_ffn() {
    __shared__ bf16 As[2][128 * 32];
    __shared__ bf16 Bs[2][128 * 32];
    ACC_INIT
    int z = blockIdx.z;
    long row0 = (long)blockIdx.x * 128, col0 = (long)blockIdx.y * 128;
    gemm128(g_h1b, DIM, g_wffT, DIM, row0, col0, z * 128, z * 128 + 128, As, Bs, acc);
    float* out = g_part + (long)z * MP;
#pragma unroll
    for (int mi = 0; mi < 4; mi++)
#pragma unroll
        for (int ni = 0; ni < 4; ni++) {
            long col = col0 + wc * 64 + ni * 16 + fr;
#pragma unroll
            for (int r = 0; r < 4; r++) {
                long row = row0 + wr * 64 + mi * 16 + fq * 4 + r;
                out[row * DIM + col] = acc[mi][ni][r];
            }
        }
}

// ---------------- layernorms (fused split-K reduction + bias) ----------------
__device__ inline float blockReduceSum(float v, float* red, int tid) {
#pragma unroll
    for (int o = 32; o > 0; o >>= 1) v += __shfl_xor(v, o);
    __syncthreads();
    if ((tid & 63) == 0) red[tid >> 6] = v;
    __syncthreads();
    return red[0] + red[1] + red[2] + red[3];
}

__global__ __launch_bounds__(256) void k_ln1(const float* __restrict__ seed,
                                             const float* __restrict__ gamma,
                                             const float* __restrict__ beta) {
    __shared__ float red[4];
    int r = blockIdx.x, t = threadIdx.x;
    int s = r & 31;
    long base = (long)r * DIM;
    float v0 = seed[s * DIM + t] + g_bvo[t];
    float v1 = seed[s * DIM + 256 + t] + g_bvo[256 + t];
#pragma unroll
    for (int z = 0; z < 4; z++) {
        v0 += g_part[(long)z * MP + base + t];
        v1 += g_part[(long)z * MP + base + 256 + t];
    }
    float mean = blockReduceSum(v0 + v1, red, t) * (1.0f / DIM);
    float d0 = v0 - mean, d1 = v1 - mean;
    float var = blockReduceSum(d0 * d0 + d1 * d1, red, t) * (1.0f / DIM);
    float ri = rsqrtf(var + 1e-5f);
    float o0 = d0 * ri * gamma[t] + beta[t];
    float o1 = d1 * ri * gamma[256 + t] + beta[256 + t];
    g_h1[base + t] = o0; g_h1[base + 256 + t] = o1;
    g_h1b[base + t] = __float2bfloat16(o0);
    g_h1b[base + 256 + t] = __float2bfloat16(o1);
}

__global__ __launch_bounds__(256) void k_ln2(const float* __restrict__ gamma,
                                             const float* __restrict__ beta,
                                             const float* __restrict__ bff,
                                             float* __restrict__ out) {
    __shared__ float red[4];
    int r = blockIdx.x, t = threadIdx.x;
    long base = (long)r * DIM;
    float v0 = g_h1[base + t] + bff[t];
    float v1 = g_h1[base + 256 + t] + bff[256 + t];
#pragma unroll
    for (int z = 0; z < 4; z++) {
        v0 += g_part[(long)z * MP + base + t];
        v1 += g_part[(long)z * MP + base + 256 + t];
    }
    float mean = blockReduceSum(v0 + v1, red, t) * (1.0f / DIM);
    float d0 = v0 - mean, d1 = v1 - mean;
    float var = blockReduceSum(d0 * d0 + d1 * d1, red, t) * (1.0f / DIM);
    float ri = rsqrtf(var + 1e-5f);
    out[base + t] = d0 * ri * gamma[t] + beta[t];
    out[base + 256 + t] = d1 * ri * gamma[256 + t] + beta[256 + t];
}

// ---------------- launch ----------------
extern "C" void kernel_launch(void* const* d_in, const int* in_sizes, int n_in,
                              void* d_out, int out_size, void* d_ws, size_t ws_size,
                              hipStream_t stream) {
    (void)in_sizes; (void)n_in; (void)out_size; (void)d_ws; (void)ws_size;
    const float* x    = (const float*)d_in[1];
    const int*   ei   = (const int*)d_in[2];
    const int*   esrc = ei;
    const int*   edst = ei + NE;
    const float* seed = (const float*)d_in[4];
    const float* Wk   = (const float*)d_in[5];
    const float* Wv   = (const float*)d_in[7];
    const float* bv   = (const float*)d_in[8];
    const float* Wq   = (const float*)d_in[9];
    const float* Wo   = (const float*)d_in[10];
    const float* bo   = (const float*)d_in[11];
    const float* Wff  = (const float*)d_in[12];
    const float* bff  = (const float*)d_in[13];
    const float* gh   = (const float*)d_in[14];
    const float* bh   = (const float*)d_in[15];
    const float* gz   = (const float*)d_in[16];
    const float* bz   = (const float*)d_in[17];
    float* out = (float*)d_out;

    k_zero   <<<NN / 256, 256, 0, stream>>>();
    k_cntprep<<<2498, 256, 0, stream>>>(edst, seed, Wq, Wo, Wv, Wff, bo, bv);
    k_scan   <<<1, 1024, 0, stream>>>();
    k_fillxb <<<10880, 256, 0, stream>>>(esrc, edst, x, Wk);
    k_gather <<<NN / 4, 256, 0, stream>>>();
    k_aggsc  <<<512 + BN * 64, 256, 0, stream>>>();
    k_soft   <<<1024, 256, 0, stream>>>();
    k_pvg    <<<512, 256, 0, stream>>>();
    k_vo     <<<dim3(16, 4, 4), 256, 0, stream>>>();
    k_ln1    <<<BN * NS, 256, 0, stream>>>(seed, gh, bh);
    k_ffn    <<<dim3(16, 4, 4), 256, 0, stream>>>();
    k_ln2    <<<BN * NS, 256, 0, stream>>>(gz, bz, bff, out);
}

// Round 9
// 229.356 us; speedup vs baseline: 1.2181x; 1.1056x over previous
//
#include <hip/hip_runtime.h>
#include <hip/hip_bf16.h>

#define BN   64
#define MAXN 512
#define DIM  512
#define NH   8
#define NS   32
#define NN   32768      // BN*MAXN
#define NE   524288
#define NBLK 256            // histogram blocks
#define EPB  (NE / NBLK)    // 2048 edges per block
#define MP   (2048 * 512)   // one partial slice

typedef __hip_bfloat16 bf16;
using bf16x8 = __attribute__((ext_vector_type(8))) short;   // 8 bf16 (4 VGPRs)
using f32x4  = __attribute__((ext_vector_type(4))) float;

// ---- persistent device scratch ----
__device__ int            g_cnt[NN];
__device__ int            g_off[NN + 1];
__device__ int            g_csr[NE];
__device__ unsigned short g_hist[(long)NBLK * NN];   // 16 MB
__device__ unsigned short g_bpfx[(long)NBLK * NN];   // 16 MB
__device__ float g_dinv[NN];
__device__ bf16  g_xb[NN * DIM];             // 32 MB
__device__ bf16  g_agg[NN * DIM];            // 32 MB
__device__ bf16  g_aggT[NN * DIM];           // 32 MB [b][d][n]
__device__ bf16  g_qf[256 * DIM];            // QF[h*32+s][d]
__device__ bf16  g_wob[DIM * DIM];           // Wo bf16
__device__ bf16  g_wvb[DIM * DIM];           // Wv bf16
__device__ bf16  g_wvo[DIM * 8 * DIM];       // 4 MB [e][h*512+d]
__device__ float g_bvo[DIM];
__device__ bf16  g_wffT[DIM * DIM];
__device__ float g_q[NS * DIM];
__device__ bf16  g_sc[BN * 256 * MAXN];      // scores -> P (in-place softmax)
__device__ bf16  g_cp[BN * NS * 8 * DIM];    // ctxpre [b*32+s][h*512+d]
__device__ float g_part[4 * MP];             // split-K partials
__device__ float g_h1[BN * NS * DIM];
__device__ bf16  g_h1b[BN * NS * DIM];

__device__ inline float bf2f(unsigned short u) {
    union { unsigned int i; float f; } x; x.i = ((unsigned int)u) << 16; return x.f;
}

__device__ inline void gll16(const bf16* g, bf16* l) {
    __builtin_amdgcn_global_load_lds(
        (const __attribute__((address_space(1))) void*)g,
        (__attribute__((address_space(3))) void*)l, 16, 0, 0);
}

// ---------------- atomic-free CSR build ----------------
// stage 1: per-block LDS histogram of dst
__global__ __launch_bounds__(512) void k_hist(const int* __restrict__ dst) {
    __shared__ unsigned int h[NN];               // 128 KB
    int p = blockIdx.x, tid = threadIdx.x;
    for (int i = tid; i < NN; i += 512) h[i] = 0;
    __syncthreads();
#pragma unroll
    for (int j = 0; j < EPB / 512; j++) {
        int e = p * EPB + j * 512 + tid;
        atomicAdd(&h[dst[e]], 1u);
    }
    __syncthreads();
    unsigned short* out = g_hist + (long)p * NN;
    for (int i = tid; i < NN; i += 512) out[i] = (unsigned short)h[i];
}

// stage 2: per-node prefix across blocks -> bpfx, totals -> cnt, dinv
__global__ __launch_bounds__(256) void k_colscan() {
    int v = blockIdx.x * 256 + threadIdx.x;
    unsigned int s = 0;
#pragma unroll 8
    for (int p = 0; p < NBLK; p++) {
        unsigned int hh = g_hist[(long)p * NN + v];
        g_bpfx[(long)p * NN + v] = (unsigned short)s;
        s += hh;
    }
    g_cnt[v] = (int)s;
    g_dinv[v] = rsqrtf(1.0f + (float)s);
}

// stage 3: exclusive scan of counts -> offsets
__global__ void k_scan() {
    __shared__ int part[1024];
    int t = threadIdx.x;
    int base = t * 32;
    int loc[32]; int s = 0;
#pragma unroll
    for (int i = 0; i < 32; i++) { loc[i] = g_cnt[base + i]; s += loc[i]; }
    part[t] = s; __syncthreads();
    for (int o = 1; o < 1024; o <<= 1) {
        int v = (t >= o) ? part[t - o] : 0;
        __syncthreads();
        part[t] += v;
        __syncthreads();
    }
    int ex = (t == 0) ? 0 : part[t - 1];
#pragma unroll
    for (int i = 0; i < 32; i++) { g_off[base + i] = ex; ex += loc[i]; }
    if (t == 1023) g_off[NN] = ex;
}

// stage 4: deterministic placement via LDS rank counters (no global atomics)
__global__ __launch_bounds__(512) void k_fillsort(const int* __restrict__ src,
                                                  const int* __restrict__ dst) {
    __shared__ unsigned int l[NN];               // 128 KB
    int p = blockIdx.x, tid = threadIdx.x;
    const unsigned short* bp = g_bpfx + (long)p * NN;
    for (int i = tid; i < NN; i += 512) l[i] = bp[i];
    __syncthreads();
#pragma unroll
    for (int j = 0; j < EPB / 512; j++) {
        int e = p * EPB + j * 512 + tid;
        int v = dst[e];
        unsigned int r = atomicAdd(&l[v], 1u);
        g_csr[g_off[v] + r] = src[e];
    }
}

// ---------------- prep: qproj (64 blk) | weight cvt (384) | bvo (2) ----------------
__global__ __launch_bounds__(256) void k_prep(const float* __restrict__ seed,
                                              const float* __restrict__ Wq,
                                              const float* __restrict__ Wo,
                                              const float* __restrict__ Wv,
                                              const float* __restrict__ Wff,
                                              const float* __restrict__ bo,
                                              const float* __restrict__ bv) {
    int blk = blockIdx.x;
    if (blk < 64) {                       // q[s][e] = seed[s].Wq[e] / 8
        int i = blk * 256 + threadIdx.x;
        int s = i >> 9, e = i & 511;
        const float* sr = seed + s * DIM;
        const float* wr = Wq + e * DIM;
        float a0 = 0.f, a1 = 0.f;
        for (int d = 0; d < DIM; d += 8) {
            float4 a = *(const float4*)(sr + d);
            float4 b = *(const float4*)(wr + d);
            float4 c = *(const float4*)(sr + d + 4);
            float4 w = *(const float4*)(wr + d + 4);
            a0 += a.x * b.x + a.y * b.y + a.z * b.z + a.w * b.w;
            a1 += c.x * w.x + c.y * w.y + c.z * w.z + c.w * w.w;
        }
        g_q[i] = (a0 + a1) * 0.125f;
    } else if (blk < 448) {               // f32 -> bf16 weight convert
        long t = (long)(blk - 64) * 256 + threadIdx.x;
        const float* src; bf16* dstp; long off;
        if (t < 32768)      { src = Wo;  dstp = g_wob;  off = t; }
        else if (t < 65536) { src = Wv;  dstp = g_wvb;  off = t - 32768; }
        else                { src = Wff; dstp = g_wffT; off = t - 65536; }
        long i = off * 8;
        float4 a = *(const float4*)(src + i);
        float4 b = *(const float4*)(src + i + 4);
        float v[8] = {a.x, a.y, a.z, a.w, b.x, b.y, b.z, b.w};
        bf16x8 o;
#pragma unroll
        for (int j = 0; j < 8; j++) { bf16 q = __float2bfloat16(v[j]); o[j] = *(short*)&q; }
        *(bf16x8*)(dstp + i) = o;
    } else {                              // bvo[e] = bo[e] + bv . Wo[e]
        int e = (blk - 448) * 256 + threadIdx.x;
        const float* orow = Wo + (long)e * DIM;
        float a0 = 0.f, a1 = 0.f;
        for (int c = 0; c < DIM; c += 8) {
            float4 a = *(const float4*)(bv + c);
            float4 w = *(const float4*)(orow + c);
            float4 xx = *(const float4*)(bv + c + 4);
            float4 u = *(const float4*)(orow + c + 4);
            a0 += a.x * w.x + a.y * w.y + a.z * w.z + a.w * w.w;
            a1 += xx.x * u.x + xx.y * u.y + xx.z * u.z + xx.w * u.w;
        }
        g_bvo[e] = bo[e] + a0 + a1;
    }
}

// ---------------- shared 128x128 MFMA GEMM core (swizzled gll + dbuf) ----------------
__device__ __forceinline__ void gemm128(const bf16* __restrict__ A, long lda,
                                        const bf16* __restrict__ Bt, long ldb,
                                        long row0, long col0, int kbeg, int kend,
                                        bf16 (*As)[128 * 32], bf16 (*Bs)[128 * 32],
                                        f32x4 acc[4][4]) {
    int tid = threadIdx.x;
    int lane = tid & 63, wave = tid >> 6;
    int wr = wave >> 1, wc = wave & 1;
    int fr = lane & 15, fq = lane >> 4;
    int rchunk = (fq ^ ((fr >> 1) & 3)) * 8;
    int u0 = wave * 128 + lane;
    int sr0 = u0 >> 2, sc0 = ((u0 & 3) ^ ((sr0 >> 1) & 3)) * 8;
    int u1 = u0 + 64;
    int sr1 = u1 >> 2, sc1 = ((u1 & 3) ^ ((sr1 >> 1) & 3)) * 8;

    auto stage = [&](int buf, int kt) {
        gll16(A + (row0 + sr0) * lda + kt + sc0, As[buf] + u0 * 8);
        gll16(A + (row0 + sr1) * lda + kt + sc1, As[buf] + u1 * 8);
        gll16(Bt + (col0 + sr0) * ldb + kt + sc0, Bs[buf] + u0 * 8);
        gll16(Bt + (col0 + sr1) * ldb + kt + sc1, Bs[buf] + u1 * 8);
    };

    stage(0, kbeg);
    __syncthreads();
    for (int kt = kbeg; kt < kend; kt += 32) {
        int buf = ((kt - kbeg) >> 5) & 1;
        if (kt + 32 < kend) stage(buf ^ 1, kt + 32);
        bf16x8 af[4], bfv[4];
#pragma unroll
        for (int mi = 0; mi < 4; mi++)
            af[mi] = *(const bf16x8*)(As[buf] + (wr * 64 + mi * 16 + fr) * 32 + rchunk);
#pragma unroll
        for (int ni = 0; ni < 4; ni++)
            bfv[ni] = *(const bf16x8*)(Bs[buf] + (wc * 64 + ni * 16 + fr) * 32 + rchunk);
#pragma unroll
        for (int mi = 0; mi < 4; mi++)
#pragma unroll
            for (int ni = 0; ni < 4; ni++)
                acc[mi][ni] = __builtin_amdgcn_mfma_f32_16x16x32_bf16(af[mi], bfv[ni], acc[mi][ni], 0, 0, 0);
        __syncthreads();
    }
}

#define ACC_INIT                                             \
    f32x4 acc[4][4];                                         \
    _Pragma("unroll")                                        \
    for (int i = 0; i < 4; i++)                              \
        _Pragma("unroll")                                    \
        for (int j = 0; j < 4; j++) acc[i][j] = (f32x4){0.f, 0.f, 0.f, 0.f}; \
    int lane = threadIdx.x & 63, wave = threadIdx.x >> 6;    \
    int wr = wave >> 1, wc = wave & 1;                       \
    int fr = lane & 15, fq = lane >> 4;

// merged: xb (8192 blk) | qf (512) | wvo (128)
__global__ __launch_bounds__(256) void k_xbqf(const float* __restrict__ x,
                                              const float* __restrict__ Wk) {
    __shared__ bf16 As[2][128 * 32];
    __shared__ bf16 Bs[2][128 * 32];
    int blk = blockIdx.x;
    if (blk < 8192) {                     // xb = bf16(x * dinv)
        long i = (long)blk * (256 * 8) + (long)threadIdx.x * 8;
        int node = (int)(i >> 9);
        float w = g_dinv[node];
        float4 a = *(const float4*)(x + i);
        float4 b = *(const float4*)(x + i + 4);
        float v[8] = {a.x, a.y, a.z, a.w, b.x, b.y, b.z, b.w};
        bf16x8 o;
#pragma unroll
        for (int j = 0; j < 8; j++) { bf16 t = __float2bfloat16(v[j] * w); o[j] = *(short*)&t; }
        *(bf16x8*)(g_xb + i) = o;
    } else if (blk < 8704) {              // QF[hs][d]
        int i = (blk - 8192) * 256 + threadIdx.x;
        int hs = i >> 9, d = i & 511;
        int h = hs >> 5, s = hs & 31;
        const float* qr = g_q + s * DIM + h * 64;
        const float* wr = Wk + d * DIM + h * 64;
        float a0 = 0.f, a1 = 0.f;
        for (int t2 = 0; t2 < 64; t2 += 8) {
            float4 a = *(const float4*)(qr + t2);
            float4 w = *(const float4*)(wr + t2);
            float4 c = *(const float4*)(qr + t2 + 4);
            float4 u = *(const float4*)(wr + t2 + 4);
            a0 += a.x * w.x + a.y * w.y + a.z * w.z + a.w * w.w;
            a1 += c.x * u.x + c.y * u.y + c.z * u.z + c.w * u.w;
        }
        g_qf[i] = __float2bfloat16(a0 + a1);
    } else {                              // Wvo GEMM, batched per head (K=64)
        int wi = blk - 8704;
        int bx = wi & 3, by = (wi >> 2) & 3, h = wi >> 4;
        ACC_INIT
        long row0 = (long)bx * 128, col0 = (long)by * 128;
        gemm128(g_wob, DIM, g_wvb, DIM, row0, col0, h * 64, h * 64 + 64, As, Bs, acc);
#pragma unroll
        for (int mi = 0; mi < 4; mi++)
#pragma unroll
            for (int ni = 0; ni < 4; ni++) {
                long col = col0 + wc * 64 + ni * 16 + fr;
#pragma unroll
                for (int r = 0; r < 4; r++) {
                    long row = row0 + wr * 64 + mi * 16 + fq * 4 + r;
                    g_wvo[row * 4096 + h * 512 + col] = __float2bfloat16(acc[mi][ni][r]);
                }
            }
    }
}

// gather (unroll 8): agg[d] = bf16( dinv[d] * ( xb[d] + sum xb[src] ) )
__global__ __launch_bounds__(256) void k_gather() {
    int bid = blockIdx.x;
    int lb = (bid & 7) * 1024 + (bid >> 3);
    int wave = threadIdx.x >> 6, lane = threadIdx.x & 63;
    int node = lb * 4 + wave;

    bf16x8 sv = ((const bf16x8*)(g_xb + (long)node * DIM))[lane];
    float acc[8];
#pragma unroll
    for (int j = 0; j < 8; j++) acc[j] = bf2f((unsigned short)sv[j]);

    int e = g_off[node], e1 = g_off[node + 1];
    for (; e + 8 <= e1; e += 8) {
        bf16x8 r[8];
#pragma unroll
        for (int q = 0; q < 8; q++)
            r[q] = ((const bf16x8*)(g_xb + (long)g_csr[e + q] * DIM))[lane];
#pragma unroll
        for (int j = 0; j < 8; j++) {
            float s01 = bf2f((unsigned short)r[0][j]) + bf2f((unsigned short)r[1][j]);
            float s23 = bf2f((unsigned short)r[2][j]) + bf2f((unsigned short)r[3][j]);
            float s45 = bf2f((unsigned short)r[4][j]) + bf2f((unsigned short)r[5][j]);
            float s67 = bf2f((unsigned short)r[6][j]) + bf2f((unsigned short)r[7][j]);
            acc[j] += (s01 + s23) + (s45 + s67);
        }
    }
    for (; e < e1; e++) {
        bf16x8 r0 = ((const bf16x8*)(g_xb + (long)g_csr[e] * DIM))[lane];
#pragma unroll
        for (int j = 0; j < 8; j++) acc[j] += bf2f((unsigned short)r0[j]);
    }
    float dd = g_dinv[node];
    bf16x8 o;
#pragma unroll
    for (int j = 0; j < 8; j++) { bf16 t = __float2bfloat16(acc[j] * dd); o[j] = *(short*)&t; }
    ((bf16x8*)(g_agg + (long)node * DIM))[lane] = o;
}

// merged: scores (512 blk, graph-major XCD swizzle) | aggT (4096 blk)
__global__ __launch_bounds__(256) void k_aggsc() {
    __shared__ __align__(16) char smem[32768];
    int blk = blockIdx.x;
    if (blk < 512) {                      // scores: C[hs][n] = QF . agg_b^T
        bf16 (*As)[128 * 32] = (bf16(*)[128 * 32])smem;
        bf16 (*Bs)[128 * 32] = (bf16(*)[128 * 32])(smem + 16384);
        int b = blk & 63, bx = (blk >> 6) & 1, by = blk >> 7;
        ACC_INIT
        long row0 = (long)bx * 128, col0 = (long)by * 128;
        gemm128(g_qf, DIM, g_agg + (long)b * (MAXN * DIM), DIM, row0, col0, 0, DIM, As, Bs, acc);
        bf16* out = g_sc + (long)b * (256 * MAXN);
#pragma unroll
        for (int mi = 0; mi < 4; mi++)
#pragma unroll
            for (int ni = 0; ni < 4; ni++) {
                long col = col0 + wc * 64 + ni * 16 + fr;
#pragma unroll
                for (int r = 0; r < 4; r++) {
                    long row = row0 + wr * 64 + mi * 16 + fq * 4 + r;
                    out[row * MAXN + col] = __float2bfloat16(acc[mi][ni][r]);
                }
            }
    } else {                              // aggT[b][d][n] = agg[b*512+n][d]
        unsigned short (*L)[72] = (unsigned short(*)[72])smem;
        int id = blk - 512;
        int b = id >> 6, t = id & 63;
        int n0 = (t & 7) * 64, d0 = (t >> 3) * 64;
        int tid = threadIdx.x;
        const unsigned short* src = (const unsigned short*)g_agg + ((long)b * 512 + n0) * 512 + d0;
#pragma unroll
        for (int p = 0; p < 2; p++) {
            int r = (tid >> 3) + 32 * p, c = (tid & 7) * 8;
            *(int4*)&L[r][c] = *(const int4*)(src + (long)r * 512 + c);
        }
        __syncthreads();
        unsigned short* dst = (unsigned short*)g_aggT + ((long)b * 512 + d0) * 512 + n0;
#pragma unroll
        for (int p = 0; p < 2; p++) {
            int dr = (tid >> 3) + 32 * p, c0 = (tid & 7) * 8;
            unsigned short tmp[8];
#pragma unroll
            for (int j = 0; j < 8; j++) tmp[j] = L[c0 + j][dr];
            *(int4*)(dst + (long)dr * 512 + c0) = *(int4*)tmp;
        }
    }
}

// in-place row softmax on g_sc (16384 rows of 512)
__global__ __launch_bounds__(256) void k_soft() {
    int w = threadIdx.x >> 6, lane = threadIdx.x & 63;
    unsigned short* base = (unsigned short*)g_sc + ((long)blockIdx.x * 16 + w * 4) * MAXN;
#pragma unroll
    for (int r = 0; r < 4; r++) {
        unsigned short* row = base + (long)r * MAXN;
        float v[8]; float m = -1e30f;
#pragma unroll
        for (int k = 0; k < 8; k++) { v[k] = bf2f(row[lane + 64 * k]); m = fmaxf(m, v[k]); }
#pragma unroll
        for (int o = 32; o > 0; o >>= 1) m = fmaxf(m, __shfl_xor(m, o));
        float sum = 0.f;
#pragma unroll
        for (int k = 0; k < 8; k++) { v[k] = __expf(v[k] - m); sum += v[k]; }
#pragma unroll
        for (int o = 32; o > 0; o >>= 1) sum += __shfl_xor(sum, o);
        float inv = 1.0f / sum;
#pragma unroll
        for (int k = 0; k < 8; k++) {
            bf16 t = __float2bfloat16(v[k] * inv);
            row[lane + 64 * k] = *(unsigned short*)&t;
        }
    }
}

// ctxpre: per (b,dh): C[hs][d] = P_b[hs][:] . aggT_b[dh*256+d][:]  (graph-major swizzle)
__global__ __launch_bounds__(256) void k_pvg() {
    __shared__ bf16 As[2][128 * 32];
    __shared__ bf16 Bs[2][128 * 32];
    int blk = blockIdx.x;
    int b = blk & 63, bx = (blk >> 6) & 1, by = (blk >> 7) & 1, dh = blk >> 8;
    ACC_INIT
    long row0 = (long)bx * 128, col0 = (long)by * 128;
    gemm128(g_sc + (long)b * (256 * MAXN), MAXN,
            g_aggT + (long)b * (DIM * MAXN) + (long)dh * (256 * MAXN), MAXN,
            row0, col0, 0, MAXN, As, Bs, acc);
#pragma unroll
    for (int mi = 0; mi < 4; mi++)
#pragma unroll
        for (int ni = 0; ni < 4; ni++) {
            long col = col0 + wc * 64 + ni * 16 + fr;
#pragma unroll
            for (int r = 0; r < 4; r++) {
                long row = row0 + wr * 64 + mi * 16 + fq * 4 + r;   // hs
                g_cp[((long)b * NS + (row & 31)) * 4096 + (row >> 5) * 512 + dh * 256 + col] =
                    __float2bfloat16(acc[mi][ni][r]);
            }
        }
}

// attn_out partials: A=g_cp [2048][4096], Bt=g_wvo [512][4096], 4-way split-K
__global__ __launch_bounds__(256) void k_vo() {
    __shared__ bf16 As[2][128 * 32];
    __shared__ bf16 Bs[2][128 * 32];
    ACC_INIT
    int z = blockIdx.z;
    long row0 = (long)blockIdx.x * 128, col0 = (long)blockIdx.y * 128;
    gemm128(g_cp, 4096, g_wvo, 4096, row0, col0, z * 1024, z * 1024 + 1024, As, Bs, acc);
    float* out = g_part + (long)z * MP;
#pragma unroll
    for (int mi = 0; mi < 4; mi++)
#pragma unroll
        for (int ni = 0; ni < 4; ni++) {
            long col = col0 + wc * 64 + ni * 16 + fr;
#pragma unroll
            for (int r = 0; r < 4; r++) {
                long row = row0 + wr * 64 + mi * 16 + fq * 4 + r;
                out[row * DIM + col] = acc[mi][ni][r];
            }
        }
}

// FFN partials: A=g_h1b [2048][512], Bt=g_wffT [512][512], 4-way split-K
__global__ __launch_bounds__(256) void k_ffn() {
    __shared__ bf16 As[2][128 * 32];
    __shared__ bf16 Bs[2][128 * 32];
    ACC_INIT
    int z = blockIdx.z;
    long row0 = (long)blockIdx.x * 128, col0 = (long)blockIdx.y * 128;
    gemm128(g_h1b, DIM, g_wffT, DIM, row0, col0, z * 128, z * 128 + 128, As, Bs, acc);
    float* out = g_part + (long)z * MP;
#pragma unroll
    for (int mi = 0; mi < 4; mi++)
#pragma unroll
        for (int ni = 0; ni < 4; ni++) {
            long col = col0 + wc * 64 + ni * 16 + fr;
#pragma unroll
            for (int r = 0; r < 4; r++) {
                long row = row0 + wr * 64 + mi * 16 + fq * 4 + r;
                out[row * DIM + col] = acc[mi][ni][r];
            }
        }
}

// ---------------- layernorms (fused split-K reduction + bias) ----------------
__device__ inline float blockReduceSum(float v, float* red, int tid) {
#pragma unroll
    for (int o = 32; o > 0; o >>= 1) v += __shfl_xor(v, o);
    __syncthreads();
    if ((tid & 63) == 0) red[tid >> 6] = v;
    __syncthreads();
    return red[0] + red[1] + red[2] + red[3];
}

__global__ __launch_bounds__(256) void k_ln1(const float* __restrict__ seed,
                                             const float* __restrict__ gamma,
                                             const float* __restrict__ beta) {
    __shared__ float red[4];
    int r = blockIdx.x, t = threadIdx.x;
    int s = r & 31;
    long base = (long)r * DIM;
    float v0 = seed[s * DIM + t] + g_bvo[t];
    float v1 = seed[s * DIM + 256 + t] + g_bvo[256 + t];
#pragma unroll
    for (int z = 0; z < 4; z++) {
        v0 += g_part[(long)z * MP + base + t];
        v1 += g_part[(long)z * MP + base + 256 + t];
    }
    float mean = blockReduceSum(v0 + v1, red, t) * (1.0f / DIM);
    float d0 = v0 - mean, d1 = v1 - mean;
    float var = blockReduceSum(d0 * d0 + d1 * d1, red, t) * (1.0f / DIM);
    float ri = rsqrtf(var + 1e-5f);
    float o0 = d0 * ri * gamma[t] + beta[t];
    float o1 = d1 * ri * gamma[256 + t] + beta[256 + t];
    g_h1[base + t] = o0; g_h1[base + 256 + t] = o1;
    g_h1b[base + t] = __float2bfloat16(o0);
    g_h1b[base + 256 + t] = __float2bfloat16(o1);
}

__global__ __launch_bounds__(256) void k_ln2(const float* __restrict__ gamma,
                                             const float* __restrict__ beta,
                                             const float* __restrict__ bff,
                                             float* __restrict__ out) {
    __shared__ float red[4];
    int r = blockIdx.x, t = threadIdx.x;
    long base = (long)r * DIM;
    float v0 = g_h1[base + t] + bff[t];
    float v1 = g_h1[base + 256 + t] + bff[256 + t];
#pragma unroll
    for (int z = 0; z < 4; z++) {
        v0 += g_part[(long)z * MP + base + t];
        v1 += g_part[(long)z * MP + base + 256 + t];
    }
    float mean = blockReduceSum(v0 + v1, red, t) * (1.0f / DIM);
    float d0 = v0 - mean, d1 = v1 - mean;
    float var = blockReduceSum(d0 * d0 + d1 * d1, red, t) * (1.0f / DIM);
    float ri = rsqrtf(var + 1e-5f);
    out[base + t] = d0 * ri * gamma[t] + beta[t];
    out[base + 256 + t] = d1 * ri * gamma[256 + t] + beta[256 + t];
}

// ---------------- launch ----------------
extern "C" void kernel_launch(void* const* d_in, const int* in_sizes, int n_in,
                              void* d_out, int out_size, void* d_ws, size_t ws_size,
                              hipStream_t stream) {
    (void)in_sizes; (void)n_in; (void)out_size; (void)d_ws; (void)ws_size;
    const float* x    = (const float*)d_in[1];
    const int*   ei   = (const int*)d_in[2];
    const int*   esrc = ei;
    const int*   edst = ei + NE;
    const float* seed = (const float*)d_in[4];
    const float* Wk   = (const float*)d_in[5];
    const float* Wv   = (const float*)d_in[7];
    const float* bv   = (const float*)d_in[8];
    const float* Wq   = (const float*)d_in[9];
    const float* Wo   = (const float*)d_in[10];
    const float* bo   = (const float*)d_in[11];
    const float* Wff  = (const float*)d_in[12];
    const float* bff  = (const float*)d_in[13];
    const float* gh   = (const float*)d_in[14];
    const float* bh   = (const float*)d_in[15];
    const float* gz   = (const float*)d_in[16];
    const float* bz   = (const float*)d_in[17];
    float* out = (float*)d_out;

    k_hist    <<<NBLK, 512, 0, stream>>>(edst);
    k_colscan <<<NN / 256, 256, 0, stream>>>();
    k_scan    <<<1, 1024, 0, stream>>>();
    k_prep    <<<450, 256, 0, stream>>>(seed, Wq, Wo, Wv, Wff, bo, bv);
    k_fillsort<<<NBLK, 512, 0, stream>>>(esrc, edst);
    k_xbqf    <<<8832, 256, 0, stream>>>(x, Wk);
    k_gather  <<<NN / 4, 256, 0, stream>>>();
    k_aggsc   <<<512 + BN * 64, 256, 0, stream>>>();
    k_soft    <<<1024, 256, 0, stream>>>();
    k_pvg     <<<512, 256, 0, stream>>>();
    k_vo      <<<dim3(16, 4, 4), 256, 0, stream>>>();
    k_ln1     <<<BN * NS, 256, 0, stream>>>(seed, gh, bh);
    k_ffn     <<<dim3(16, 4, 4), 256, 0, stream>>>();
    k_ln2     <<<BN * NS, 256, 0, stream>>>(gz, bz, bff, out);
}